// Round 6
// baseline (251.809 us; speedup 1.0000x reference)
//
#include <hip/hip_runtime.h>

// NAM: out[b,c] = bias[c] + sum_f Wout[f]^T · relu(W2[f]^T · relu(x[b,f]*W1[f] + b1[f]) + b2[f])
// B=8192, F=256, H1=64, H2=32, C=10. fp32 (no fp32-input MFMA on CDNA4).
//
// R6: R5 core was issue-stalled at 67% VALUBusy / 36% occupancy (grid capped 4 waves/SIMD;
// ~90 live floats vs VGPR=64 -> AGPR round-trips). Fix: RPT=1 (live set ~50 regs, real
// 64-VGPR fit), grid (64 fg x 32 rg) = 2048 blocks = 32 waves/CU, and drop the transpose
// kernel: each thread loads its single x float4 ONCE before the feature loop (R4's
// pathology was 16 re-gathers/thread inside the loop).

#define NB 8192
#define NF 256
#define H1 64
#define H2 32
#define NC 10
#define THREADS 256
#define FPG 4                    // features per block
#define NFG (NF / FPG)           // 64 feature-groups
#define NRG (NB / THREADS)       // 32 row-groups

__global__ __launch_bounds__(THREADS, 8) void nam_core_g(
    const float* __restrict__ x,  const float* __restrict__ W1,
    const float* __restrict__ b1, const float* __restrict__ W2,
    const float* __restrict__ b2, const float* __restrict__ Wout,
    float* __restrict__ partial) {   // [NFG][NC][NB]
    const int fg = blockIdx.x;       // fastest dim -> XCD = fg % 8 (weight L2 locality)
    const int rg = blockIdx.y;
    const int b  = rg * THREADS + threadIdx.x;
    const int f0 = fg * FPG;

    // One gather per thread, before the loop; amortized over ~9.7K FMAs.
    const float4 xv4 = *(const float4*)(x + (size_t)b * NF + f0);

    float acc[NC];
#pragma unroll
    for (int c = 0; c < NC; ++c) acc[c] = 0.f;

    // Statically inlined per-feature body (no runtime-indexed xv[] -> no scratch).
    auto do_feature = [&](const int f, const float xv) {
        // Wave-uniform weight pointers -> s_load streams, SGPR operands in v_fma.
        const float* __restrict__ W1f = W1 + (size_t)f * H1;
        const float* __restrict__ b1f = b1 + (size_t)f * H1;
        const float* __restrict__ W2f = W2 + (size_t)f * (H1 * H2);
        const float* __restrict__ b2f = b2 + (size_t)f * H2;
        const float* __restrict__ Wof = Wout + (size_t)f * (H2 * NC);

        float h2[H2];
#pragma unroll
        for (int o = 0; o < H2; ++o) h2[o] = b2f[o];

#pragma unroll 8   // 8 hh per iteration: compiler batches s_load_dwordx16 ahead
        for (int hh = 0; hh < H1; ++hh) {
            const float a = fmaxf(fmaf(xv, W1f[hh], b1f[hh]), 0.f);
            const float* wr = W2f + (size_t)hh * H2;
#pragma unroll
            for (int o = 0; o < H2; ++o)
                h2[o] = fmaf(a, wr[o], h2[o]);   // v_fmac v,v,s
        }

#pragma unroll 8
        for (int o = 0; o < H2; ++o) {
            const float g = fmaxf(h2[o], 0.f);
            const float* wo = Wof + o * NC;
#pragma unroll
            for (int c = 0; c < NC; ++c)
                acc[c] = fmaf(g, wo[c], acc[c]);
        }
    };

    do_feature(f0 + 0, xv4.x);
    do_feature(f0 + 1, xv4.y);
    do_feature(f0 + 2, xv4.z);
    do_feature(f0 + 3, xv4.w);

    // [G][NC][NB]: lane-consecutive b -> 10 coalesced 256B/wave stores.
#pragma unroll
    for (int c = 0; c < NC; ++c)
        partial[((size_t)fg * NC + c) * NB + b] = acc[c];
}

// ---- reduce 64 partials + bias -> out[NB][NC]; float4 over b ----
__global__ __launch_bounds__(256) void nam_reduce4(const float* __restrict__ part,
                                                   const float* __restrict__ bias,
                                                   float* __restrict__ out) {
    const int i  = blockIdx.x * 256 + threadIdx.x;   // over NC * NB/4 = 20480
    const int c  = i / (NB / 4);
    const int b4 = i % (NB / 4);
    const float bc = bias[c];
    float4 s = {bc, bc, bc, bc};
#pragma unroll 8
    for (int g = 0; g < NFG; ++g) {
        const float4 v = ((const float4*)(part + ((size_t)g * NC + c) * NB))[b4];
        s.x += v.x; s.y += v.y; s.z += v.z; s.w += v.w;
    }
    const int b = 4 * b4;
    out[(size_t)(b + 0) * NC + c] = s.x;
    out[(size_t)(b + 1) * NC + c] = s.y;
    out[(size_t)(b + 2) * NC + c] = s.z;
    out[(size_t)(b + 3) * NC + c] = s.w;
}

// ---- last-resort fallback (tiny ws): direct x reads + atomics ----
__global__ __launch_bounds__(256) void nam_init_out(const float* __restrict__ bias,
                                                    float* __restrict__ out) {
    const int i = blockIdx.x * 256 + threadIdx.x;
    if (i < NB * NC) out[i] = bias[i % NC];
}

__global__ __launch_bounds__(256) void nam_fallback(
    const float* __restrict__ x,  const float* __restrict__ W1,
    const float* __restrict__ b1, const float* __restrict__ W2,
    const float* __restrict__ b2, const float* __restrict__ Wout,
    float* __restrict__ out) {
    const int b  = blockIdx.x * 256 + threadIdx.x;
    const int f0 = blockIdx.y * 16;
    float acc[NC];
#pragma unroll
    for (int c = 0; c < NC; ++c) acc[c] = 0.f;
#pragma unroll 1
    for (int ff = 0; ff < 16; ++ff) {
        const int f = f0 + ff;
        const float xv = x[(size_t)b * NF + f];
        const float* W1f = W1 + (size_t)f * H1;
        const float* b1f = b1 + (size_t)f * H1;
        const float* W2f = W2 + (size_t)f * (H1 * H2);
        const float* b2f = b2 + (size_t)f * H2;
        const float* Wof = Wout + (size_t)f * (H2 * NC);
        float h2[H2];
#pragma unroll
        for (int o = 0; o < H2; ++o) h2[o] = b2f[o];
#pragma unroll 8
        for (int hh = 0; hh < H1; ++hh) {
            const float a = fmaxf(fmaf(xv, W1f[hh], b1f[hh]), 0.f);
            const float* wr = W2f + (size_t)hh * H2;
#pragma unroll
            for (int o = 0; o < H2; ++o) h2[o] = fmaf(a, wr[o], h2[o]);
        }
#pragma unroll
        for (int o = 0; o < H2; ++o) {
            const float g = fmaxf(h2[o], 0.f);
            const float* wo = Wof + o * NC;
#pragma unroll
            for (int c = 0; c < NC; ++c) acc[c] = fmaf(g, wo[c], acc[c]);
        }
    }
    float* orow = out + (size_t)b * NC;
#pragma unroll
    for (int c = 0; c < NC; ++c) atomicAdd(&orow[c], acc[c]);
}

extern "C" void kernel_launch(void* const* d_in, const int* in_sizes, int n_in,
                              void* d_out, int out_size, void* d_ws, size_t ws_size,
                              hipStream_t stream) {
    const float* x    = (const float*)d_in[0];
    const float* W1   = (const float*)d_in[1];
    const float* b1   = (const float*)d_in[2];
    const float* W2   = (const float*)d_in[3];
    const float* b2   = (const float*)d_in[4];
    const float* Wout = (const float*)d_in[5];
    const float* bias = (const float*)d_in[6];
    float* out = (float*)d_out;

    float* part = (float*)d_ws;  // [NFG][NC][NB] = 21.0 MB
    const size_t need = (size_t)NFG * NC * NB * sizeof(float);

    if (ws_size >= need) {
        nam_core_g<<<dim3(NFG, NRG), THREADS, 0, stream>>>(x, W1, b1, W2, b2, Wout, part);
        nam_reduce4<<<(NC * NB / 4 + 255) / 256, 256, 0, stream>>>(part, bias, out);
    } else {
        nam_init_out<<<(NB * NC + 255) / 256, 256, 0, stream>>>(bias, out);
        nam_fallback<<<dim3(NB / 256, 16), 256, 0, stream>>>(x, W1, b1, W2, b2, Wout, out);
    }
}

// Round 12
// 180.173 us; speedup vs baseline: 1.3976x; 1.3976x over previous
//
#include <hip/hip_runtime.h>

// NAM: out[b,c] = bias[c] + sum_f Wout[f]^T · relu(W2[f]^T · relu(x[b,f]*W1[f] + b1[f]) + b2[f])
// B=8192, F=256, H1=64, H2=32, C=10. fp32 (no fp32-input MFMA on CDNA4).
//
// R7: R5 body verbatim (VGPR=64, zero spill: FETCH 6.6MB / WRITE == partials exactly),
// but FPG=2 -> 2048 blocks = 8 blocks/CU = 8 waves/SIMD (R5 idled 33% at 4/SIMD).
// R6 lesson: launch_bounds(256,8)'s 64-VGPR cap => VGPR=32 + h2 scratch-spill
// (FETCH 155MB/WRITE 305MB). Stay at (256,4); it's a min-waves guarantee, not a max —
// hardware fills to 8 blocks/CU at VGPR=64.

#define NB 8192
#define NF 256
#define H1 64
#define H2 32
#define NC 10
#define THREADS 256
#define ROWSPB (THREADS * 2)     // 2 rows/thread
#define NRG (NB / ROWSPB)        // 16 row-groups
#define TS 64                    // transpose tile

// ---- x[B][F] -> xT[F][B], LDS-tiled, fully coalesced both sides ----
__global__ __launch_bounds__(256) void nam_transpose(const float* __restrict__ x,
                                                     float* __restrict__ xT) {
    __shared__ float tile[TS][TS + 1];
    const int t  = threadIdx.x;
    const int c0 = t & 63;
    const int r0 = t >> 6;
    const int bb = blockIdx.x * TS;
    const int fb = blockIdx.y * TS;
#pragma unroll
    for (int k = 0; k < 16; ++k) {
        const int r = r0 + k * 4;
        tile[r][c0] = x[(size_t)(bb + r) * NF + fb + c0];
    }
    __syncthreads();
#pragma unroll
    for (int k = 0; k < 16; ++k) {
        const int r = r0 + k * 4;
        xT[(size_t)(fb + r) * NB + bb + c0] = tile[c0][r];
    }
}

// ---- main: one thread = 2 rows x FPG features; weights via wave-uniform s_load ----
template <int FPG>
__global__ __launch_bounds__(THREADS, 4) void nam_core_t(
    const float* __restrict__ xT, const float* __restrict__ W1,
    const float* __restrict__ b1, const float* __restrict__ W2,
    const float* __restrict__ b2, const float* __restrict__ Wout,
    float* __restrict__ partial) {   // [NF/FPG][NC][NB]
    const int fg = blockIdx.x;       // fastest dim -> XCD = fg % 8 (weight L2 locality)
    const int rg = blockIdx.y;
    const int t  = threadIdx.x;
    const int r0 = rg * ROWSPB + t;
    const int r1 = r0 + THREADS;
    const int f0 = fg * FPG;

    float acc0[NC], acc1[NC];
#pragma unroll
    for (int c = 0; c < NC; ++c) { acc0[c] = 0.f; acc1[c] = 0.f; }

#pragma unroll 1
    for (int ff = 0; ff < FPG; ++ff) {
        const int f = f0 + ff;
        const float xv0 = xT[(size_t)f * NB + r0];   // coalesced, L2-resident
        const float xv1 = xT[(size_t)f * NB + r1];
        // Wave-uniform weight pointers -> s_load streams, SGPR operands in v_fma.
        const float* __restrict__ W1f = W1 + (size_t)f * H1;
        const float* __restrict__ b1f = b1 + (size_t)f * H1;
        const float* __restrict__ W2f = W2 + (size_t)f * (H1 * H2);
        const float* __restrict__ b2f = b2 + (size_t)f * H2;
        const float* __restrict__ Wof = Wout + (size_t)f * (H2 * NC);

        float h2a[H2], h2b[H2];
#pragma unroll
        for (int o = 0; o < H2; ++o) { const float bb_ = b2f[o]; h2a[o] = bb_; h2b[o] = bb_; }

#pragma unroll 8
        for (int hh = 0; hh < H1; ++hh) {
            const float a0 = fmaxf(fmaf(xv0, W1f[hh], b1f[hh]), 0.f);
            const float a1 = fmaxf(fmaf(xv1, W1f[hh], b1f[hh]), 0.f);
            const float* wr = W2f + (size_t)hh * H2;
#pragma unroll
            for (int o = 0; o < H2; ++o) {
                const float w = wr[o];          // SGPR
                h2a[o] = fmaf(a0, w, h2a[o]);
                h2b[o] = fmaf(a1, w, h2b[o]);
            }
        }

#pragma unroll 8
        for (int o = 0; o < H2; ++o) {
            const float g0 = fmaxf(h2a[o], 0.f), g1 = fmaxf(h2b[o], 0.f);
            const float* wo = Wof + o * NC;
#pragma unroll
            for (int c = 0; c < NC; ++c) {
                const float w = wo[c];
                acc0[c] = fmaf(g0, w, acc0[c]);
                acc1[c] = fmaf(g1, w, acc1[c]);
            }
        }
    }

#pragma unroll
    for (int c = 0; c < NC; ++c) {   // [G][NC][NB]: 256B/wave coalesced stores
        partial[((size_t)fg * NC + c) * NB + r0] = acc0[c];
        partial[((size_t)fg * NC + c) * NB + r1] = acc1[c];
    }
}

// ---- reduce G partials + bias -> out[NB][NC]; float4 over b ----
template <int G>
__global__ __launch_bounds__(256) void nam_reduce4(const float* __restrict__ part,
                                                   const float* __restrict__ bias,
                                                   float* __restrict__ out) {
    const int i  = blockIdx.x * 256 + threadIdx.x;   // over NC * NB/4 = 20480
    const int c  = i / (NB / 4);
    const int b4 = i % (NB / 4);
    const float bc = bias[c];
    float4 s = {bc, bc, bc, bc};
#pragma unroll 8
    for (int g = 0; g < G; ++g) {
        const float4 v = ((const float4*)(part + ((size_t)g * NC + c) * NB))[b4];
        s.x += v.x; s.y += v.y; s.z += v.z; s.w += v.w;
    }
    const int b = 4 * b4;
    out[(size_t)(b + 0) * NC + c] = s.x;
    out[(size_t)(b + 1) * NC + c] = s.y;
    out[(size_t)(b + 2) * NC + c] = s.z;
    out[(size_t)(b + 3) * NC + c] = s.w;
}

// ---- last-resort fallback (tiny ws): direct x reads + atomics ----
__global__ __launch_bounds__(256) void nam_init_out(const float* __restrict__ bias,
                                                    float* __restrict__ out) {
    const int i = blockIdx.x * 256 + threadIdx.x;
    if (i < NB * NC) out[i] = bias[i % NC];
}

__global__ __launch_bounds__(256) void nam_fallback(
    const float* __restrict__ x,  const float* __restrict__ W1,
    const float* __restrict__ b1, const float* __restrict__ W2,
    const float* __restrict__ b2, const float* __restrict__ Wout,
    float* __restrict__ out) {
    const int b  = blockIdx.x * 256 + threadIdx.x;
    const int f0 = blockIdx.y * 16;
    float acc[NC];
#pragma unroll
    for (int c = 0; c < NC; ++c) acc[c] = 0.f;
#pragma unroll 1
    for (int ff = 0; ff < 16; ++ff) {
        const int f = f0 + ff;
        const float xv = x[(size_t)b * NF + f];
        const float* W1f = W1 + (size_t)f * H1;
        const float* b1f = b1 + (size_t)f * H1;
        const float* W2f = W2 + (size_t)f * (H1 * H2);
        const float* b2f = b2 + (size_t)f * H2;
        const float* Wof = Wout + (size_t)f * (H2 * NC);
        float h2[H2];
#pragma unroll
        for (int o = 0; o < H2; ++o) h2[o] = b2f[o];
#pragma unroll 8
        for (int hh = 0; hh < H1; ++hh) {
            const float a = fmaxf(fmaf(xv, W1f[hh], b1f[hh]), 0.f);
            const float* wr = W2f + (size_t)hh * H2;
#pragma unroll
            for (int o = 0; o < H2; ++o) h2[o] = fmaf(a, wr[o], h2[o]);
        }
#pragma unroll
        for (int o = 0; o < H2; ++o) {
            const float g = fmaxf(h2[o], 0.f);
            const float* wo = Wof + o * NC;
#pragma unroll
            for (int c = 0; c < NC; ++c) acc[c] = fmaf(g, wo[c], acc[c]);
        }
    }
    float* orow = out + (size_t)b * NC;
#pragma unroll
    for (int c = 0; c < NC; ++c) atomicAdd(&orow[c], acc[c]);
}

extern "C" void kernel_launch(void* const* d_in, const int* in_sizes, int n_in,
                              void* d_out, int out_size, void* d_ws, size_t ws_size,
                              hipStream_t stream) {
    const float* x    = (const float*)d_in[0];
    const float* W1   = (const float*)d_in[1];
    const float* b1   = (const float*)d_in[2];
    const float* W2   = (const float*)d_in[3];
    const float* b2   = (const float*)d_in[4];
    const float* Wout = (const float*)d_in[5];
    const float* bias = (const float*)d_in[6];
    float* out = (float*)d_out;

    // ws layout: [xT: NF*NB][partials: (NF/FPG)*NC*NB]
    float* xT   = (float*)d_ws;
    float* part = xT + (size_t)NF * NB;
    const size_t need2 = ((size_t)NF * NB + (size_t)128 * NC * NB) * sizeof(float); // 50.3MB
    const size_t need4 = ((size_t)NF * NB + (size_t)64  * NC * NB) * sizeof(float); // 29.4MB
    const int nred = (NC * NB / 4 + 255) / 256;

    if (ws_size >= need2) {
        // FPG=2: 128x16 = 2048 blocks = 8 blocks/CU = 8 waves/SIMD at VGPR=64.
        nam_transpose<<<dim3(NB / TS, NF / TS), 256, 0, stream>>>(x, xT);
        nam_core_t<2><<<dim3(128, NRG), THREADS, 0, stream>>>(xT, W1, b1, W2, b2, Wout, part);
        nam_reduce4<128><<<nred, 256, 0, stream>>>(part, bias, out);
    } else if (ws_size >= need4) {
        // R5-exact tier (tells us ws_size is in [29.4, 50.3) MB).
        nam_transpose<<<dim3(NB / TS, NF / TS), 256, 0, stream>>>(x, xT);
        nam_core_t<4><<<dim3(64, NRG), THREADS, 0, stream>>>(xT, W1, b1, W2, b2, Wout, part);
        nam_reduce4<64><<<nred, 256, 0, stream>>>(part, bias, out);
    } else {
        nam_init_out<<<(NB * NC + 255) / 256, 256, 0, stream>>>(bias, out);
        nam_fallback<<<dim3(NB / 256, 16), 256, 0, stream>>>(x, W1, b1, W2, b2, Wout, out);
    }
}

// Round 13
// 179.791 us; speedup vs baseline: 1.4006x; 1.0021x over previous
//
#include <hip/hip_runtime.h>

// NAM: out[b,c] = bias[c] + sum_f Wout[f]^T · relu(W2[f]^T · relu(x[b,f]*W1[f] + b1[f]) + b2[f])
// B=8192, F=256, H1=64, H2=32, C=10. fp32 (no fp32-input MFMA on CDNA4).
//
// R13: occupancy attack. R12 showed 36% occupancy at 2048 blocks/(256,4)/VGPR=64 while
// R4's (256,8) showed 85% -> suspect waves-per-eu attr cap and/or AGPR shadow-alloc
// (90 live floats can't fit 64 arch VGPRs). Fix: RPT=1 (live ~50 regs: weights are
// SGPR-resident, RPT=2 never saved VGPR traffic), NO second launch_bounds arg, and
// 4096 blocks (128fg x 32rg). Keep xT (FETCH 130->6.6MB proven) + fg%8 XCD pinning.

#define NB 8192
#define NF 256
#define H1 64
#define H2 32
#define NC 10
#define THREADS 256
#define TS 64                    // transpose tile

// ---- x[B][F] -> xT[F][B], LDS-tiled, fully coalesced both sides ----
__global__ __launch_bounds__(256) void nam_transpose(const float* __restrict__ x,
                                                     float* __restrict__ xT) {
    __shared__ float tile[TS][TS + 1];
    const int t  = threadIdx.x;
    const int c0 = t & 63;
    const int r0 = t >> 6;
    const int bb = blockIdx.x * TS;
    const int fb = blockIdx.y * TS;
#pragma unroll
    for (int k = 0; k < 16; ++k) {
        const int r = r0 + k * 4;
        tile[r][c0] = x[(size_t)(bb + r) * NF + fb + c0];
    }
    __syncthreads();
#pragma unroll
    for (int k = 0; k < 16; ++k) {
        const int r = r0 + k * 4;
        xT[(size_t)(fb + r) * NB + bb + c0] = tile[c0][r];
    }
}

// ---- main: one thread = 1 row x FPG features; weights via wave-uniform s_load ----
// No second launch_bounds arg: let HW fill waves to the VGPR limit (~50 live regs).
template <int FPG>
__global__ __launch_bounds__(THREADS) void nam_core_v2(
    const float* __restrict__ xT, const float* __restrict__ W1,
    const float* __restrict__ b1, const float* __restrict__ W2,
    const float* __restrict__ b2, const float* __restrict__ Wout,
    float* __restrict__ partial) {   // [NF/FPG][NC][NB]
    const int fg = blockIdx.x;       // fastest dim -> XCD = (fg + 128*rg) % 8 = fg % 8
    const int rg = blockIdx.y;
    const int b  = rg * THREADS + threadIdx.x;
    const int f0 = fg * FPG;

    float acc[NC];
#pragma unroll
    for (int c = 0; c < NC; ++c) acc[c] = 0.f;

#pragma unroll 1   // keep body I$-resident (~18KB per feature)
    for (int ff = 0; ff < FPG; ++ff) {
        const int f = f0 + ff;
        const float xv = xT[(size_t)f * NB + b];   // coalesced, L2-resident
        // Wave-uniform weight pointers -> s_load streams, SGPR operands in v_fma.
        const float* __restrict__ W1f = W1 + (size_t)f * H1;
        const float* __restrict__ b1f = b1 + (size_t)f * H1;
        const float* __restrict__ W2f = W2 + (size_t)f * (H1 * H2);
        const float* __restrict__ b2f = b2 + (size_t)f * H2;
        const float* __restrict__ Wof = Wout + (size_t)f * (H2 * NC);

        float h2[H2];
#pragma unroll
        for (int o = 0; o < H2; ++o) h2[o] = b2f[o];

#pragma unroll 8   // batches s_load_dwordx16 ahead of the FMA runs
        for (int hh = 0; hh < H1; ++hh) {
            const float a = fmaxf(fmaf(xv, W1f[hh], b1f[hh]), 0.f);
            const float* wr = W2f + (size_t)hh * H2;
#pragma unroll
            for (int o = 0; o < H2; ++o)
                h2[o] = fmaf(a, wr[o], h2[o]);   // v_fmac v,v,s
        }

#pragma unroll 8
        for (int o = 0; o < H2; ++o) {
            const float g = fmaxf(h2[o], 0.f);
            const float* wo = Wof + o * NC;
#pragma unroll
            for (int c = 0; c < NC; ++c)
                acc[c] = fmaf(g, wo[c], acc[c]);
        }
    }

    // [G][NC][NB]: lane-consecutive b -> 10 coalesced 256B/wave stores.
#pragma unroll
    for (int c = 0; c < NC; ++c)
        partial[((size_t)fg * NC + c) * NB + b] = acc[c];
}

// ---- reduce G partials + bias -> out[NB][NC]; float4 over b ----
template <int G>
__global__ __launch_bounds__(256) void nam_reduce4(const float* __restrict__ part,
                                                   const float* __restrict__ bias,
                                                   float* __restrict__ out) {
    const int i  = blockIdx.x * 256 + threadIdx.x;   // over NC * NB/4 = 20480
    const int c  = i / (NB / 4);
    const int b4 = i % (NB / 4);
    const float bc = bias[c];
    float4 s = {bc, bc, bc, bc};
#pragma unroll 8
    for (int g = 0; g < G; ++g) {
        const float4 v = ((const float4*)(part + ((size_t)g * NC + c) * NB))[b4];
        s.x += v.x; s.y += v.y; s.z += v.z; s.w += v.w;
    }
    const int b = 4 * b4;
    out[(size_t)(b + 0) * NC + c] = s.x;
    out[(size_t)(b + 1) * NC + c] = s.y;
    out[(size_t)(b + 2) * NC + c] = s.z;
    out[(size_t)(b + 3) * NC + c] = s.w;
}

// ---- last-resort fallback (tiny ws): direct x reads + atomics ----
__global__ __launch_bounds__(256) void nam_init_out(const float* __restrict__ bias,
                                                    float* __restrict__ out) {
    const int i = blockIdx.x * 256 + threadIdx.x;
    if (i < NB * NC) out[i] = bias[i % NC];
}

__global__ __launch_bounds__(256) void nam_fallback(
    const float* __restrict__ x,  const float* __restrict__ W1,
    const float* __restrict__ b1, const float* __restrict__ W2,
    const float* __restrict__ b2, const float* __restrict__ Wout,
    float* __restrict__ out) {
    const int b  = blockIdx.x * 256 + threadIdx.x;
    const int f0 = blockIdx.y * 16;
    float acc[NC];
#pragma unroll
    for (int c = 0; c < NC; ++c) acc[c] = 0.f;
#pragma unroll 1
    for (int ff = 0; ff < 16; ++ff) {
        const int f = f0 + ff;
        const float xv = x[(size_t)b * NF + f];
        const float* W1f = W1 + (size_t)f * H1;
        const float* b1f = b1 + (size_t)f * H1;
        const float* W2f = W2 + (size_t)f * (H1 * H2);
        const float* b2f = b2 + (size_t)f * H2;
        const float* Wof = Wout + (size_t)f * (H2 * NC);
        float h2[H2];
#pragma unroll
        for (int o = 0; o < H2; ++o) h2[o] = b2f[o];
#pragma unroll 8
        for (int hh = 0; hh < H1; ++hh) {
            const float a = fmaxf(fmaf(xv, W1f[hh], b1f[hh]), 0.f);
            const float* wr = W2f + (size_t)hh * H2;
#pragma unroll
            for (int o = 0; o < H2; ++o) h2[o] = fmaf(a, wr[o], h2[o]);
        }
#pragma unroll
        for (int o = 0; o < H2; ++o) {
            const float g = fmaxf(h2[o], 0.f);
            const float* wo = Wof + o * NC;
#pragma unroll
            for (int c = 0; c < NC; ++c) acc[c] = fmaf(g, wo[c], acc[c]);
        }
    }
    float* orow = out + (size_t)b * NC;
#pragma unroll
    for (int c = 0; c < NC; ++c) atomicAdd(&orow[c], acc[c]);
}

extern "C" void kernel_launch(void* const* d_in, const int* in_sizes, int n_in,
                              void* d_out, int out_size, void* d_ws, size_t ws_size,
                              hipStream_t stream) {
    const float* x    = (const float*)d_in[0];
    const float* W1   = (const float*)d_in[1];
    const float* b1   = (const float*)d_in[2];
    const float* W2   = (const float*)d_in[3];
    const float* b2   = (const float*)d_in[4];
    const float* Wout = (const float*)d_in[5];
    const float* bias = (const float*)d_in[6];
    float* out = (float*)d_out;

    // ws layout: [xT: NF*NB][partials: (NF/FPG)*NC*NB]
    float* xT   = (float*)d_ws;
    float* part = xT + (size_t)NF * NB;
    const size_t need2 = ((size_t)NF * NB + (size_t)128 * NC * NB) * sizeof(float); // 50.3MB
    const size_t need4 = ((size_t)NF * NB + (size_t)64  * NC * NB) * sizeof(float); // 29.4MB
    const int nred = (NC * NB / 4 + 255) / 256;

    if (ws_size >= need2) {
        // FPG=2, RPT=1: 128 x 32 = 4096 blocks -> fill CUs to the HW wave limit.
        nam_transpose<<<dim3(NB / TS, NF / TS), 256, 0, stream>>>(x, xT);
        nam_core_v2<2><<<dim3(128, NB / THREADS), THREADS, 0, stream>>>(
            xT, W1, b1, W2, b2, Wout, part);
        nam_reduce4<128><<<nred, 256, 0, stream>>>(part, bias, out);
    } else if (ws_size >= need4) {
        nam_transpose<<<dim3(NB / TS, NF / TS), 256, 0, stream>>>(x, xT);
        nam_core_v2<4><<<dim3(64, NB / THREADS), THREADS, 0, stream>>>(
            xT, W1, b1, W2, b2, Wout, part);
        nam_reduce4<64><<<nred, 256, 0, stream>>>(part, bias, out);
    } else {
        nam_init_out<<<(NB * NC + 255) / 256, 256, 0, stream>>>(bias, out);
        nam_fallback<<<dim3(NB / 256, 16), 256, 0, stream>>>(x, W1, b1, W2, b2, Wout, out);
    }
}